// Round 1
// baseline (4299.181 us; speedup 1.0000x reference)
//
#include <hip/hip_runtime.h>
#include <math.h>

// Problem constants (LSTMBasedTextDecoder): B=32, T=128, E=256, H=512, ENC=512, V=10000
#define Bx   32
#define Tx   128
#define Ex   256
#define Hx   512
#define ENCx 512
#define Vx   10000
#define G4   2048   // 4*H

__device__ __forceinline__ float sigm(float x) { return 1.0f / (1.0f + expf(-x)); }

// ---------------------------------------------------------------------------
// K0: o = tv@Wo^T+b, h0 = tv@Wh^T+b, c0 = tv@Wc^T+b.
// o stored [b][j]; h0,c0 stored transposed [j][b] (batch-fastest) for the
// recurrence's coalesced reads. Tiny kernel (3*32*512 outputs, K=512).
// ---------------------------------------------------------------------------
__global__ __launch_bounds__(256) void k_init(
    const float* __restrict__ tv,
    const float* __restrict__ Wo_w, const float* __restrict__ Wo_b,
    const float* __restrict__ Wh_w, const float* __restrict__ Wh_b,
    const float* __restrict__ Wc_w, const float* __restrict__ Wc_b,
    float* __restrict__ o, float* __restrict__ h0, float* __restrict__ c0) {
  int tid = blockIdx.x * blockDim.x + threadIdx.x;   // 3*B*H = 49152
  int which = tid / (Bx * Hx);
  int r = tid - which * (Bx * Hx);
  int b = r >> 9, j = r & (Hx - 1);
  const float* W; const float* bias;
  if (which == 0)      { W = Wo_w; bias = Wo_b; }
  else if (which == 1) { W = Wh_w; bias = Wh_b; }
  else                 { W = Wc_w; bias = Wc_b; }
  const float* x = tv + b * ENCx;
  const float* w = W + (size_t)j * ENCx;
  float acc = bias[j];
#pragma unroll 8
  for (int k = 0; k < ENCx; k++) acc += x[k] * w[k];
  if (which == 0)      o[b * Hx + j] = acc;
  else if (which == 1) h0[j * Bx + b] = acc;
  else                 c0[j * Bx + b] = acc;
}

// ---------------------------------------------------------------------------
// K1: constT[g][b] = b_ih[g] + b_hh[g] + o[b,:]·W_ih[g,256:768] + tv[b,:]·W_ih[g,768:1280]
// (the step-invariant part of the gate preactivation). Stored batch-fastest.
// ---------------------------------------------------------------------------
__global__ __launch_bounds__(256) void k_const(
    const float* __restrict__ tv, const float* __restrict__ o,
    const float* __restrict__ W_ih, const float* __restrict__ b_ih,
    const float* __restrict__ b_hh, float* __restrict__ constT) {
  int tid = blockIdx.x * blockDim.x + threadIdx.x;   // B*G4 = 65536
  int b = tid >> 11, g = tid & (G4 - 1);
  const float* w = W_ih + (size_t)g * (Ex + Hx + ENCx);
  float acc = b_ih[g] + b_hh[g];
  const float* ob = o + b * Hx;
#pragma unroll 8
  for (int k = 0; k < Hx; k++) acc += ob[k] * w[Ex + k];
  const float* xb = tv + b * ENCx;
#pragma unroll 8
  for (int k = 0; k < ENCx; k++) acc += xb[k] * w[Ex + Hx + k];
  constT[g * Bx + b] = acc;
}

// ---------------------------------------------------------------------------
// K2: Gy[t][g][b] = emb[token(b,t)] · W_ih[g, 0:256]
// token(b,0)=start_idx, token(b,t)=texts[b][t-1] (teacher forcing → all known
// up front). Tiled fp32 GEMM: M=T*B=4096 (m=t*32+b), N=2048, K=256.
// 128x128 tile, 256 threads, 8x8 acc per thread, K-tile 8.
// ---------------------------------------------------------------------------
#define TM 128
#define TN 128
#define TK 8

__global__ __launch_bounds__(256) void k_gy(
    const float* __restrict__ emb, const int* __restrict__ texts,
    const int* __restrict__ start_idx, const float* __restrict__ W_ih,
    float* __restrict__ Gy) {
  __shared__ float As[TK][TM + 1];
  __shared__ float Bs[TK][TN + 1];
  const int n0 = blockIdx.x * TN;
  const int m0 = blockIdx.y * TM;
  const int q = threadIdx.x;
  const int tx = q & 15, ty = q >> 4;
  const int lrow = q >> 1, lk = (q & 1) * 4;   // 2 threads load one 8-wide K row

  const int am = m0 + lrow;
  const int at = am >> 5, ab = am & 31;
  const int tok = (at == 0) ? start_idx[0] : texts[ab * Tx + at - 1];
  const float* arow_ptr = emb + (size_t)tok * Ex;
  const float* brow_ptr = W_ih + (size_t)(n0 + lrow) * (Ex + Hx + ENCx);

  float acc[8][8] = {};
  for (int k0 = 0; k0 < Ex; k0 += TK) {
    __syncthreads();
    float4 av = *(const float4*)(arow_ptr + k0 + lk);
    float4 bv = *(const float4*)(brow_ptr + k0 + lk);
    As[lk + 0][lrow] = av.x; As[lk + 1][lrow] = av.y;
    As[lk + 2][lrow] = av.z; As[lk + 3][lrow] = av.w;
    Bs[lk + 0][lrow] = bv.x; Bs[lk + 1][lrow] = bv.y;
    Bs[lk + 2][lrow] = bv.z; Bs[lk + 3][lrow] = bv.w;
    __syncthreads();
#pragma unroll
    for (int kk = 0; kk < TK; kk++) {
      float a[8], bb[8];
#pragma unroll
      for (int i = 0; i < 8; i++) a[i] = As[kk][ty * 8 + i];
#pragma unroll
      for (int j = 0; j < 8; j++) bb[j] = Bs[kk][tx * 8 + j];
#pragma unroll
      for (int i = 0; i < 8; i++)
#pragma unroll
        for (int j = 0; j < 8; j++) acc[i][j] += a[i] * bb[j];
    }
  }
  // store Gy[t][n][b], m = t*32 + b
#pragma unroll
  for (int i = 0; i < 8; i++) {
    int m = m0 + ty * 8 + i;
    int t = m >> 5, b = m & 31;
    size_t base = (size_t)t * (G4 * Bx) + b;
#pragma unroll
    for (int j = 0; j < 8; j++) {
      int n = n0 + tx * 8 + j;
      Gy[base + (size_t)n * Bx] = acc[i][j];
    }
  }
}

// ---------------------------------------------------------------------------
// K3 (x128, sequential): one LSTM step.
// pre[b,g] = Gy[t][g][b] + constT[g][b] + h[b,:]·W_hh[g,:]
// Thread per (b,j): 4 gate dots of K=512. h/c stored [j][b] → lane b-fastest
// reads coalesce; W_hh row reads broadcast across the 32 same-j lanes.
// ---------------------------------------------------------------------------
__global__ __launch_bounds__(128) void k_step(
    const float* __restrict__ Gy, const float* __restrict__ constT,
    const float* __restrict__ W_hh, const float* __restrict__ h_in,
    float* __restrict__ h_out, float* __restrict__ c,
    float* __restrict__ hs2, int t) {
  int tid = blockIdx.x * blockDim.x + threadIdx.x;  // 16384
  int b = tid & 31, j = tid >> 5;
  const float* GyT = Gy + (size_t)t * (G4 * Bx);
  int idx = j * Bx + b;
  float ai = GyT[idx]                + constT[idx];
  float af = GyT[idx +     Hx * Bx]  + constT[idx +     Hx * Bx];
  float ag = GyT[idx + 2 * Hx * Bx]  + constT[idx + 2 * Hx * Bx];
  float ao = GyT[idx + 3 * Hx * Bx]  + constT[idx + 3 * Hx * Bx];
  const float* wi = W_hh + (size_t)j * Hx;
  const float* wf = wi + (size_t)Hx * Hx;
  const float* wg = wf + (size_t)Hx * Hx;
  const float* wo = wg + (size_t)Hx * Hx;
#pragma unroll 8
  for (int k = 0; k < Hx; k++) {
    float hk = h_in[k * Bx + b];
    ai += hk * wi[k]; af += hk * wf[k];
    ag += hk * wg[k]; ao += hk * wo[k];
  }
  float ig = sigm(ai), fg = sigm(af), gg = tanhf(ag), og = sigm(ao);
  float cn = fg * c[idx] + ig * gg;
  c[idx] = cn;
  float hn = og * tanhf(cn);
  h_out[idx] = hn;
  // hs stored [b][t][j] (row-major A for the projection GEMM)
  hs2[(size_t)b * (Tx * Hx) + (size_t)t * Hx + j] = hn;
}

// ---------------------------------------------------------------------------
// K4: logits[b,t,v] = hs[b,t,:]·Wv_w[v,:] + Wv_b[v]
// Tiled fp32 GEMM: M=4096 (m=b*T+t), N=10000, K=512. 128x128 tile, 8x8/thread.
// ---------------------------------------------------------------------------
__global__ __launch_bounds__(256) void k_proj(
    const float* __restrict__ Am, const float* __restrict__ Bw,
    const float* __restrict__ bias, float* __restrict__ Cm) {
  __shared__ float As[TK][TM + 1];
  __shared__ float Bs[TK][TN + 1];
  const int n0 = blockIdx.x * TN;
  const int m0 = blockIdx.y * TM;
  const int q = threadIdx.x;
  const int tx = q & 15, ty = q >> 4;
  const int lrow = q >> 1, lk = (q & 1) * 4;

  const float* arow_ptr = Am + (size_t)(m0 + lrow) * Hx;
  const int bn = n0 + lrow;
  const float* brow_ptr = Bw + (size_t)bn * Hx;
  const bool bvalid = (bn < Vx);

  float acc[8][8] = {};
  for (int k0 = 0; k0 < Hx; k0 += TK) {
    __syncthreads();
    float4 av = *(const float4*)(arow_ptr + k0 + lk);
    float4 bv = make_float4(0.f, 0.f, 0.f, 0.f);
    if (bvalid) bv = *(const float4*)(brow_ptr + k0 + lk);
    As[lk + 0][lrow] = av.x; As[lk + 1][lrow] = av.y;
    As[lk + 2][lrow] = av.z; As[lk + 3][lrow] = av.w;
    Bs[lk + 0][lrow] = bv.x; Bs[lk + 1][lrow] = bv.y;
    Bs[lk + 2][lrow] = bv.z; Bs[lk + 3][lrow] = bv.w;
    __syncthreads();
#pragma unroll
    for (int kk = 0; kk < TK; kk++) {
      float a[8], bb[8];
#pragma unroll
      for (int i = 0; i < 8; i++) a[i] = As[kk][ty * 8 + i];
#pragma unroll
      for (int j = 0; j < 8; j++) bb[j] = Bs[kk][tx * 8 + j];
#pragma unroll
      for (int i = 0; i < 8; i++)
#pragma unroll
        for (int j = 0; j < 8; j++) acc[i][j] += a[i] * bb[j];
    }
  }
#pragma unroll
  for (int i = 0; i < 8; i++) {
    int m = m0 + ty * 8 + i;
    float* crow = Cm + (size_t)m * Vx;
#pragma unroll
    for (int j = 0; j < 8; j++) {
      int n = n0 + tx * 8 + j;
      if (n < Vx) crow[n] = acc[i][j] + bias[n];
    }
  }
}

// ---------------------------------------------------------------------------
// Inputs (setup_inputs order):
//  0 text_vectors [32,512] f32   1 texts [32,128] i32   2 lengths [32] i32 (unused)
//  3 start_idx scalar i32        4 emb_table [10000,256] f32
//  5 W_ih [2048,1280] f32  6 b_ih [2048]  7 W_hh [2048,512]  8 b_hh [2048]
//  9 Wo_w [512,512] 10 Wo_b  11 Wh_w 12 Wh_b  13 Wc_w 14 Wc_b
// 15 Wv_w [10000,512] 16 Wv_b [10000]
// Output: logits [32,128,10000] f32 (40,960,000 elements)
// Workspace: 10,616,832 floats ≈ 42.5 MB
// ---------------------------------------------------------------------------
extern "C" void kernel_launch(void* const* d_in, const int* in_sizes, int n_in,
                              void* d_out, int out_size, void* d_ws, size_t ws_size,
                              hipStream_t stream) {
  const float* tv     = (const float*)d_in[0];
  const int*   texts  = (const int*)d_in[1];
  const int*   sidx   = (const int*)d_in[3];
  const float* emb    = (const float*)d_in[4];
  const float* W_ih   = (const float*)d_in[5];
  const float* b_ih   = (const float*)d_in[6];
  const float* W_hh   = (const float*)d_in[7];
  const float* b_hh   = (const float*)d_in[8];
  const float* Wo_w   = (const float*)d_in[9];
  const float* Wo_b   = (const float*)d_in[10];
  const float* Wh_w   = (const float*)d_in[11];
  const float* Wh_b   = (const float*)d_in[12];
  const float* Wc_w   = (const float*)d_in[13];
  const float* Wc_b   = (const float*)d_in[14];
  const float* Wv_w   = (const float*)d_in[15];
  const float* Wv_b   = (const float*)d_in[16];
  float* out = (float*)d_out;

  float* ws     = (float*)d_ws;
  float* o      = ws;                       // B*H       = 16384
  float* hb0    = o      + Bx * Hx;         // H*B       = 16384
  float* hb1    = hb0    + Hx * Bx;         // H*B       = 16384
  float* c      = hb1    + Hx * Bx;         // H*B       = 16384
  float* constT = c      + Hx * Bx;         // G4*B      = 65536
  float* Gy     = constT + G4 * Bx;         // T*G4*B    = 8388608
  float* hs2    = Gy + (size_t)Tx * G4 * Bx;// B*T*H     = 2097152

  hipLaunchKernelGGL(k_init, dim3(192), dim3(256), 0, stream,
                     tv, Wo_w, Wo_b, Wh_w, Wh_b, Wc_w, Wc_b, o, hb0, c);
  hipLaunchKernelGGL(k_const, dim3(256), dim3(256), 0, stream,
                     tv, o, W_ih, b_ih, b_hh, constT);
  hipLaunchKernelGGL(k_gy, dim3(G4 / TN, (Tx * Bx) / TM), dim3(256), 0, stream,
                     emb, texts, sidx, W_ih, Gy);
  for (int t = 0; t < Tx; t++) {
    float* hin  = (t & 1) ? hb1 : hb0;
    float* hout = (t & 1) ? hb0 : hb1;
    hipLaunchKernelGGL(k_step, dim3(128), dim3(128), 0, stream,
                       Gy, constT, W_hh, hin, hout, c, hs2, t);
  }
  hipLaunchKernelGGL(k_proj, dim3((Vx + TN - 1) / TN, (Bx * Tx) / TM), dim3(256), 0, stream,
                     hs2, Wv_w, Wv_b, out);
}

// Round 2
// 2169.944 us; speedup vs baseline: 1.9812x; 1.9812x over previous
//
#include <hip/hip_runtime.h>
#include <math.h>

// Problem constants (LSTMBasedTextDecoder): B=32, T=128, E=256, H=512, ENC=512, V=10000
#define Bx   32
#define Tx   128
#define Ex   256
#define Hx   512
#define ENCx 512
#define Vx   10000
#define G4   2048   // 4*H

typedef __bf16 bf16x8 __attribute__((ext_vector_type(8)));
typedef float  f32x4  __attribute__((ext_vector_type(4)));

__device__ __forceinline__ float sigm(float x) { return 1.0f / (1.0f + expf(-x)); }

// ---------------------------------------------------------------------------
// K0: o = tv@Wo^T+b, h0 = tv@Wh^T+b, c0 = tv@Wc^T+b.
// o stored [b][j]; h0,c0 stored transposed [j][b] (batch-fastest).
// ---------------------------------------------------------------------------
__global__ __launch_bounds__(256) void k_init(
    const float* __restrict__ tv,
    const float* __restrict__ Wo_w, const float* __restrict__ Wo_b,
    const float* __restrict__ Wh_w, const float* __restrict__ Wh_b,
    const float* __restrict__ Wc_w, const float* __restrict__ Wc_b,
    float* __restrict__ o, float* __restrict__ h0, float* __restrict__ c0) {
  int tid = blockIdx.x * blockDim.x + threadIdx.x;   // 3*B*H = 49152
  int which = tid / (Bx * Hx);
  int r = tid - which * (Bx * Hx);
  int b = r >> 9, j = r & (Hx - 1);
  const float* W; const float* bias;
  if (which == 0)      { W = Wo_w; bias = Wo_b; }
  else if (which == 1) { W = Wh_w; bias = Wh_b; }
  else                 { W = Wc_w; bias = Wc_b; }
  const float* x = tv + b * ENCx;
  const float* w = W + (size_t)j * ENCx;
  float acc = bias[j];
#pragma unroll 8
  for (int k = 0; k < ENCx; k++) acc += x[k] * w[k];
  if (which == 0)      o[b * Hx + j] = acc;
  else if (which == 1) h0[j * Bx + b] = acc;
  else                 c0[j * Bx + b] = acc;
}

// ---------------------------------------------------------------------------
// K1: constT[g][b] = step-invariant part of gate preactivation.
// ---------------------------------------------------------------------------
__global__ __launch_bounds__(256) void k_const(
    const float* __restrict__ tv, const float* __restrict__ o,
    const float* __restrict__ W_ih, const float* __restrict__ b_ih,
    const float* __restrict__ b_hh, float* __restrict__ constT) {
  int tid = blockIdx.x * blockDim.x + threadIdx.x;   // B*G4 = 65536
  int b = tid >> 11, g = tid & (G4 - 1);
  const float* w = W_ih + (size_t)g * (Ex + Hx + ENCx);
  float acc = b_ih[g] + b_hh[g];
  const float* ob = o + b * Hx;
#pragma unroll 8
  for (int k = 0; k < Hx; k++) acc += ob[k] * w[Ex + k];
  const float* xb = tv + b * ENCx;
#pragma unroll 8
  for (int k = 0; k < ENCx; k++) acc += xb[k] * w[Ex + Hx + k];
  constT[g * Bx + b] = acc;
}

// ---------------------------------------------------------------------------
// K2: Gy[t][g][b] = emb[token(b,t)] · W_ih[g, 0:256]   (teacher-forced tokens,
// all known up front). fp32 tiled GEMM, M=4096 (m=t*32+b), N=2048, K=256.
// ---------------------------------------------------------------------------
#define TM 128
#define TN 128
#define TK 8

__global__ __launch_bounds__(256) void k_gy(
    const float* __restrict__ emb, const int* __restrict__ texts,
    const int* __restrict__ start_idx, const float* __restrict__ W_ih,
    float* __restrict__ Gy) {
  __shared__ float As[TK][TM + 1];
  __shared__ float Bs[TK][TN + 1];
  const int n0 = blockIdx.x * TN;
  const int m0 = blockIdx.y * TM;
  const int q = threadIdx.x;
  const int tx = q & 15, ty = q >> 4;
  const int lrow = q >> 1, lk = (q & 1) * 4;

  const int am = m0 + lrow;
  const int at = am >> 5, ab = am & 31;
  const int tok = (at == 0) ? start_idx[0] : texts[ab * Tx + at - 1];
  const float* arow_ptr = emb + (size_t)tok * Ex;
  const float* brow_ptr = W_ih + (size_t)(n0 + lrow) * (Ex + Hx + ENCx);

  float acc[8][8] = {};
  for (int k0 = 0; k0 < Ex; k0 += TK) {
    __syncthreads();
    float4 av = *(const float4*)(arow_ptr + k0 + lk);
    float4 bv = *(const float4*)(brow_ptr + k0 + lk);
    As[lk + 0][lrow] = av.x; As[lk + 1][lrow] = av.y;
    As[lk + 2][lrow] = av.z; As[lk + 3][lrow] = av.w;
    Bs[lk + 0][lrow] = bv.x; Bs[lk + 1][lrow] = bv.y;
    Bs[lk + 2][lrow] = bv.z; Bs[lk + 3][lrow] = bv.w;
    __syncthreads();
#pragma unroll
    for (int kk = 0; kk < TK; kk++) {
      float a[8], bb[8];
#pragma unroll
      for (int i = 0; i < 8; i++) a[i] = As[kk][ty * 8 + i];
#pragma unroll
      for (int j = 0; j < 8; j++) bb[j] = Bs[kk][tx * 8 + j];
#pragma unroll
      for (int i = 0; i < 8; i++)
#pragma unroll
        for (int j = 0; j < 8; j++) acc[i][j] += a[i] * bb[j];
    }
  }
#pragma unroll
  for (int i = 0; i < 8; i++) {
    int m = m0 + ty * 8 + i;
    int t = m >> 5, b = m & 31;
    size_t base = (size_t)t * (G4 * Bx) + b;
#pragma unroll
    for (int j = 0; j < 8; j++) {
      int n = n0 + tx * 8 + j;
      Gy[base + (size_t)n * Bx] = acc[i][j];
    }
  }
}

// ---------------------------------------------------------------------------
// K3 (x128, sequential): one LSTM step, latency-optimized.
// Block = one h-unit u (512 blocks, 2/CU, 8 waves/CU). 256 threads =
// (s in [0,8)) x (b in [0,32)). Thread computes 4 gate partial dots over its
// 64-wide k slice; W loads are float4 broadcast per half-wave, h loads
// coalesced 128B. Reduce: shfl_xor(32) pairs s-halves, LDS for cross-wave.
// ---------------------------------------------------------------------------
__global__ __launch_bounds__(256) void k_step(
    const float* __restrict__ Gy, const float* __restrict__ constT,
    const float* __restrict__ W_hh, const float* __restrict__ h_in,
    float* __restrict__ h_out, float* __restrict__ c,
    __bf16* __restrict__ hs2, int t) {
  const int u = blockIdx.x;            // [0,512)
  const int tid = threadIdx.x;
  const int b = tid & 31, s = tid >> 5;

  const float* wi = W_hh + (size_t)u * Hx;
  const float* wf = wi + (size_t)Hx * Hx;
  const float* wg = wf + (size_t)Hx * Hx;
  const float* wo = wg + (size_t)Hx * Hx;

  float pi = 0.f, pf = 0.f, pg = 0.f, po = 0.f;
  const int kbeg = s * 64;
#pragma unroll 4
  for (int kk = 0; kk < 64; kk += 4) {
    const int k = kbeg + kk;
    float4 vi = *(const float4*)(wi + k);
    float4 vf = *(const float4*)(wf + k);
    float4 vg = *(const float4*)(wg + k);
    float4 vo = *(const float4*)(wo + k);
    float h0v = h_in[(k + 0) * Bx + b];
    float h1v = h_in[(k + 1) * Bx + b];
    float h2v = h_in[(k + 2) * Bx + b];
    float h3v = h_in[(k + 3) * Bx + b];
    pi += vi.x * h0v + vi.y * h1v + vi.z * h2v + vi.w * h3v;
    pf += vf.x * h0v + vf.y * h1v + vf.z * h2v + vf.w * h3v;
    pg += vg.x * h0v + vg.y * h1v + vg.z * h2v + vg.w * h3v;
    po += vo.x * h0v + vo.y * h1v + vo.z * h2v + vo.w * h3v;
  }

  // combine s with s^1 (lane ^ 32 within the wave)
  pi += __shfl_xor(pi, 32);
  pf += __shfl_xor(pf, 32);
  pg += __shfl_xor(pg, 32);
  po += __shfl_xor(po, 32);

  __shared__ float red[3][32][4];
  if (s != 0 && (s & 1) == 0) {        // s = 2,4,6
    const int w = (s >> 1) - 1;
    red[w][b][0] = pi; red[w][b][1] = pf;
    red[w][b][2] = pg; red[w][b][3] = po;
  }
  __syncthreads();
  if (s == 0) {
#pragma unroll
    for (int w = 0; w < 3; w++) {
      pi += red[w][b][0]; pf += red[w][b][1];
      pg += red[w][b][2]; po += red[w][b][3];
    }
    const float* GyT = Gy + (size_t)t * (G4 * Bx);
    const int idx = u * Bx + b;
    const float ai = GyT[idx]                + constT[idx]                + pi;
    const float af = GyT[idx +     Hx * Bx]  + constT[idx +     Hx * Bx]  + pf;
    const float ag = GyT[idx + 2 * Hx * Bx]  + constT[idx + 2 * Hx * Bx]  + pg;
    const float ao = GyT[idx + 3 * Hx * Bx]  + constT[idx + 3 * Hx * Bx]  + po;
    const float cn = sigm(af) * c[idx] + sigm(ai) * tanhf(ag);
    c[idx] = cn;
    const float hn = sigm(ao) * tanhf(cn);
    h_out[idx] = hn;
    hs2[((size_t)b * Tx + t) * Hx + u] = (__bf16)hn;   // A of proj GEMM, [m][k]
  }
}

// ---------------------------------------------------------------------------
// K_cvt: fp32 -> bf16 (for Wv_w). n divisible by 4.
// ---------------------------------------------------------------------------
__global__ __launch_bounds__(256) void k_cvt(
    const float* __restrict__ src, __bf16* __restrict__ dst, int n) {
  int i = (blockIdx.x * blockDim.x + threadIdx.x) * 4;
  if (i < n) {
    float4 v = *(const float4*)(src + i);
    dst[i + 0] = (__bf16)v.x; dst[i + 1] = (__bf16)v.y;
    dst[i + 2] = (__bf16)v.z; dst[i + 3] = (__bf16)v.w;
  }
}

// ---------------------------------------------------------------------------
// K4: logits = hs(bf16) @ Wv(bf16)^T + b, via MFMA 16x16x32 bf16.
// M=4096, N=10000 (tiles padded to 10112, row index clamped on load, store
// guarded), K=512. 128x128 block tile, 4 waves each 64x64 (4x4 16x16 frags).
// LDS rows padded to 40 bf16 (80 B) -> only free 2-way conflicts on b128.
// ---------------------------------------------------------------------------
#define PM 128
#define PN 128
#define PK 32
#define PKP 40   // padded LDS row (bf16 elems)

__global__ __launch_bounds__(256) void k_proj_mfma(
    const __bf16* __restrict__ A,    // [4096][512]
    const __bf16* __restrict__ Bw,   // [10000][512]
    const float* __restrict__ bias, float* __restrict__ C) {
  __shared__ __bf16 As[PM][PKP];
  __shared__ __bf16 Bs[PN][PKP];
  const int m0 = blockIdx.y * PM;
  const int n0 = blockIdx.x * PN;
  const int t = threadIdx.x;
  const int wave = t >> 6, lane = t & 63;
  const int wm = (wave & 1) * 64, wn = (wave >> 1) * 64;
  const int fm = lane & 15, fk = (lane >> 4) * 8;
  const int sr = t >> 2, sk = (t & 3) * 8;   // staging: 4 threads per row

  const int n1 = min(n0 + sr, Vx - 1);       // clamp: stores are guarded
  const int n2 = min(n0 + sr + 64, Vx - 1);

  f32x4 acc[4][4];
#pragma unroll
  for (int i = 0; i < 4; i++)
#pragma unroll
    for (int j = 0; j < 4; j++) acc[i][j] = (f32x4){0.f, 0.f, 0.f, 0.f};

  for (int k0 = 0; k0 < Hx; k0 += PK) {
    __syncthreads();
    *(bf16x8*)&As[sr][sk]      = *(const bf16x8*)&A[(size_t)(m0 + sr) * Hx + k0 + sk];
    *(bf16x8*)&As[sr + 64][sk] = *(const bf16x8*)&A[(size_t)(m0 + sr + 64) * Hx + k0 + sk];
    *(bf16x8*)&Bs[sr][sk]      = *(const bf16x8*)&Bw[(size_t)n1 * Hx + k0 + sk];
    *(bf16x8*)&Bs[sr + 64][sk] = *(const bf16x8*)&Bw[(size_t)n2 * Hx + k0 + sk];
    __syncthreads();
    bf16x8 af[4], bfr[4];
#pragma unroll
    for (int i = 0; i < 4; i++) af[i]  = *(const bf16x8*)&As[wm + i * 16 + fm][fk];
#pragma unroll
    for (int j = 0; j < 4; j++) bfr[j] = *(const bf16x8*)&Bs[wn + j * 16 + fm][fk];
#pragma unroll
    for (int i = 0; i < 4; i++)
#pragma unroll
      for (int j = 0; j < 4; j++)
        acc[i][j] = __builtin_amdgcn_mfma_f32_16x16x32_bf16(af[i], bfr[j], acc[i][j], 0, 0, 0);
  }

  // C/D layout: col = lane&15 (n), row = (lane>>4)*4 + reg (m)
  const int cr = (lane >> 4) * 4, cc = lane & 15;
#pragma unroll
  for (int i = 0; i < 4; i++) {
#pragma unroll
    for (int r = 0; r < 4; r++) {
      const int m = m0 + wm + i * 16 + cr + r;
      float* crow = C + (size_t)m * Vx;
#pragma unroll
      for (int j = 0; j < 4; j++) {
        const int n = n0 + wn + j * 16 + cc;
        if (n < Vx) crow[n] = acc[i][j][r] + bias[n];
      }
    }
  }
}

// ---------------------------------------------------------------------------
// Inputs (setup_inputs order):
//  0 text_vectors [32,512] f32   1 texts [32,128] i32   2 lengths (unused)
//  3 start_idx scalar i32        4 emb_table [10000,256] f32
//  5 W_ih [2048,1280] 6 b_ih 7 W_hh [2048,512] 8 b_hh
//  9 Wo_w 10 Wo_b 11 Wh_w 12 Wh_b 13 Wc_w 14 Wc_b 15 Wv_w [10000,512] 16 Wv_b
// Output: logits [32,128,10000] f32
// Workspace: ~48.5 MB
// ---------------------------------------------------------------------------
extern "C" void kernel_launch(void* const* d_in, const int* in_sizes, int n_in,
                              void* d_out, int out_size, void* d_ws, size_t ws_size,
                              hipStream_t stream) {
  const float* tv     = (const float*)d_in[0];
  const int*   texts  = (const int*)d_in[1];
  const int*   sidx   = (const int*)d_in[3];
  const float* emb    = (const float*)d_in[4];
  const float* W_ih   = (const float*)d_in[5];
  const float* b_ih   = (const float*)d_in[6];
  const float* W_hh   = (const float*)d_in[7];
  const float* b_hh   = (const float*)d_in[8];
  const float* Wo_w   = (const float*)d_in[9];
  const float* Wo_b   = (const float*)d_in[10];
  const float* Wh_w   = (const float*)d_in[11];
  const float* Wh_b   = (const float*)d_in[12];
  const float* Wc_w   = (const float*)d_in[13];
  const float* Wc_b   = (const float*)d_in[14];
  const float* Wv_w   = (const float*)d_in[15];
  const float* Wv_b   = (const float*)d_in[16];
  float* out = (float*)d_out;

  float* ws     = (float*)d_ws;
  float* o      = ws;                        // B*H    = 16384
  float* hb0    = o      + Bx * Hx;          // H*B
  float* hb1    = hb0    + Hx * Bx;          // H*B
  float* c      = hb1    + Hx * Bx;          // H*B
  float* constT = c      + Hx * Bx;          // G4*B   = 65536
  float* Gy     = constT + G4 * Bx;          // T*G4*B = 8388608
  __bf16* hs2   = (__bf16*)(Gy + (size_t)Tx * G4 * Bx);  // B*T*H bf16
  __bf16* Wvb   = hs2 + (size_t)Bx * Tx * Hx;            // V*H bf16

  hipLaunchKernelGGL(k_init, dim3(192), dim3(256), 0, stream,
                     tv, Wo_w, Wo_b, Wh_w, Wh_b, Wc_w, Wc_b, o, hb0, c);
  hipLaunchKernelGGL(k_const, dim3(256), dim3(256), 0, stream,
                     tv, o, W_ih, b_ih, b_hh, constT);
  hipLaunchKernelGGL(k_cvt, dim3((Vx * Hx / 4 + 255) / 256), dim3(256), 0, stream,
                     Wv_w, Wvb, Vx * Hx);
  hipLaunchKernelGGL(k_gy, dim3(G4 / TN, (Tx * Bx) / TM), dim3(256), 0, stream,
                     emb, texts, sidx, W_ih, Gy);
  for (int t = 0; t < Tx; t++) {
    float* hin  = (t & 1) ? hb1 : hb0;
    float* hout = (t & 1) ? hb0 : hb1;
    hipLaunchKernelGGL(k_step, dim3(512), dim3(256), 0, stream,
                       Gy, constT, W_hh, hin, hout, c, hs2, t);
  }
  hipLaunchKernelGGL(k_proj_mfma,
                     dim3((Vx + PN - 1) / PN, (Bx * Tx) / PM), dim3(256), 0, stream,
                     hs2, Wvb, Wv_b, out);
}

// Round 3
// 1396.865 us; speedup vs baseline: 3.0777x; 1.5534x over previous
//
#include <hip/hip_runtime.h>
#include <math.h>

// Problem constants (LSTMBasedTextDecoder): B=32, T=128, E=256, H=512, ENC=512, V=10000
#define Bx   32
#define Tx   128
#define Ex   256
#define Hx   512
#define ENCx 512
#define Vx   10000
#define G4   2048   // 4*H

#define RBLK 64     // k_rec grid: 64 blocks, 8 h-units each (co-resident, 1 per 4 SIMDs)
#define UPB  8      // h-units per block
#define KREC 768    // fused recurrence K = H (512, h) + E (256, y)
#define KPAD 776    // LDS row pitch (bf16): 1552 B = 388 banks == 4 mod 32 -> 2-way (free)

typedef __bf16 bf16x8 __attribute__((ext_vector_type(8)));
typedef float  f32x4  __attribute__((ext_vector_type(4)));

#define MFMA16 __builtin_amdgcn_mfma_f32_16x16x32_bf16

__device__ __forceinline__ float sigm(float x) { return 1.0f / (1.0f + expf(-x)); }

// ---------------------------------------------------------------------------
// K0: o = tv@Wo^T+b (fp32 [b][j]); h0 -> hglob bf16 [b][j]; c0 fp32 [j][b].
// ---------------------------------------------------------------------------
__global__ __launch_bounds__(256) void k_init(
    const float* __restrict__ tv,
    const float* __restrict__ Wo_w, const float* __restrict__ Wo_b,
    const float* __restrict__ Wh_w, const float* __restrict__ Wh_b,
    const float* __restrict__ Wc_w, const float* __restrict__ Wc_b,
    float* __restrict__ o, __bf16* __restrict__ hglob, float* __restrict__ c0) {
  int tid = blockIdx.x * blockDim.x + threadIdx.x;   // 3*B*H = 49152
  int which = tid / (Bx * Hx);
  int r = tid - which * (Bx * Hx);
  int b = r >> 9, j = r & (Hx - 1);
  const float* W; const float* bias;
  if (which == 0)      { W = Wo_w; bias = Wo_b; }
  else if (which == 1) { W = Wh_w; bias = Wh_b; }
  else                 { W = Wc_w; bias = Wc_b; }
  const float* x = tv + b * ENCx;
  const float* w = W + (size_t)j * ENCx;
  float acc = bias[j];
#pragma unroll 8
  for (int k = 0; k < ENCx; k++) acc += x[k] * w[k];
  if (which == 0)      o[b * Hx + j] = acc;
  else if (which == 1) hglob[b * Hx + j] = (__bf16)acc;
  else                 c0[j * Bx + b] = acc;
}

// ---------------------------------------------------------------------------
// K1: constC[b][g] = b_ih[g]+b_hh[g] + o[b]:W_ih[g,256:768] + tv[b]:W_ih[g,768:1280]
// (step-invariant preactivation part, fp32 exact). Also zeroes the grid-barrier
// counter (ws is re-poisoned to 0xAA before every timed call).
// ---------------------------------------------------------------------------
__global__ __launch_bounds__(256) void k_const(
    const float* __restrict__ tv, const float* __restrict__ o,
    const float* __restrict__ W_ih, const float* __restrict__ b_ih,
    const float* __restrict__ b_hh, float* __restrict__ constC,
    int* __restrict__ cnt) {
  int tid = blockIdx.x * blockDim.x + threadIdx.x;   // B*G4 = 65536
  if (tid == 0) cnt[0] = 0;
  int b = tid >> 11, g = tid & (G4 - 1);
  const float* w = W_ih + (size_t)g * (Ex + Hx + ENCx);
  float acc = b_ih[g] + b_hh[g];
  const float* ob = o + b * Hx;
#pragma unroll 8
  for (int k = 0; k < Hx; k++) acc += ob[k] * w[Ex + k];
  const float* xb = tv + b * ENCx;
#pragma unroll 8
  for (int k = 0; k < ENCx; k++) acc += xb[k] * w[Ex + Hx + k];
  constC[b * G4 + g] = acc;   // [b][g], g-fastest
}

// ---------------------------------------------------------------------------
// K_cvt: fp32 -> bf16, flat (n divisible by 4).
// ---------------------------------------------------------------------------
__global__ __launch_bounds__(256) void k_cvt(
    const float* __restrict__ src, __bf16* __restrict__ dst, int n) {
  int i = (blockIdx.x * blockDim.x + threadIdx.x) * 4;
  if (i < n) {
    float4 v = *(const float4*)(src + i);
    dst[i + 0] = (__bf16)v.x; dst[i + 1] = (__bf16)v.y;
    dst[i + 2] = (__bf16)v.z; dst[i + 3] = (__bf16)v.w;
  }
}

// K_cvt2d: W_ih[:, 0:256] (pitch 1280) -> dense bf16 [2048][256].
__global__ __launch_bounds__(256) void k_cvt2d(
    const float* __restrict__ src, __bf16* __restrict__ dst) {
  int idx = (blockIdx.x * 256 + threadIdx.x) * 4;   // 2048*256 elems
  int row = idx >> 8, col = idx & 255;
  float4 v = *(const float4*)(src + (size_t)row * 1280 + col);
  dst[idx + 0] = (__bf16)v.x; dst[idx + 1] = (__bf16)v.y;
  dst[idx + 2] = (__bf16)v.z; dst[idx + 3] = (__bf16)v.w;
}

// ---------------------------------------------------------------------------
// K2: the whole recurrence in ONE launch. 64 blocks x 256 threads, all
// co-resident (110 KB LDS -> 1 block/CU; previous stream work has drained).
// Block nb owns h-units u0..u0+7 => 32 gate rows n = ul*4+gate, staged once
// into LDS as [W_hh | W_ih[:,0:256]] bf16 (K=768). Per step: stage A=[h;y_t]
// (y teacher-forced from texts), 16x16x32 MFMA (M=32 batch, N=32 rows,
// K=768 split over 2 k-half waves), reduce, fp32 gate epilogue (c in regs),
// write h (bf16) to global, device-scope atomic grid barrier.
// ---------------------------------------------------------------------------
__global__ __launch_bounds__(256) void k_rec(
    const __bf16* __restrict__ Whb,   // [2048][512]
    const __bf16* __restrict__ Wihb,  // [2048][256]
    const __bf16* __restrict__ embb,  // [V][256]
    const int* __restrict__ texts, const int* __restrict__ sidx,
    const float* __restrict__ constC, // [32][2048]
    const float* __restrict__ c0,     // [512][32]
    __bf16* __restrict__ hglob,       // [32][512]
    __bf16* __restrict__ hs2,         // [4096][512]  row m = b*128+t
    int* __restrict__ cnt) {
  __shared__ __bf16 Ws[2 * 16][KPAD];
  __shared__ __bf16 Hs[32][KPAD];
  __shared__ float  Red[2][2][256];
  __shared__ float  Cs[32][33];
  __shared__ __bf16 Ht[32][8];

  const int q = threadIdx.x;
  const int nb = blockIdx.x;
  const int u0 = nb * UPB;
  const int lane = q & 63, wave = q >> 6;
  const int mt = wave & 1, kh = wave >> 1;          // m-tile, k-half
  const int fm = lane & 15, fk = (lane >> 4) * 8;   // MFMA frag row / k-offset
  const int s0tok = sidx[0];

  // ---- stage Ws once: LDS row n <- W row (n&3)*512 + u0 + (n>>2) ----
  {
    const int row = q >> 3;                          // 8 threads per row
    const int wr = (row & 3) * Hx + u0 + (row >> 2);
    const __bf16* wh = Whb + (size_t)wr * Hx;
    const __bf16* wy = Wihb + (size_t)wr * Ex;
#pragma unroll
    for (int r = 0; r < 12; r++) {
      const int col = ((q & 7) + 8 * r) * 8;         // 0..760
      bf16x8 v = (col < Hx) ? *(const bf16x8*)(wh + col)
                            : *(const bf16x8*)(wy + col - Hx);
      *(bf16x8*)&Ws[row][col] = v;
    }
  }

  const int eb = q & 31, eu = q >> 5;                // epilogue (batch, u_local)
  float creg = c0[(u0 + eu) * Bx + eb];
  const float* cc2 = constC + eb * G4 + u0 + eu;     // + g*512 per gate

  for (int t = 0; t < Tx; t++) {
    // ---- stage A = [h(512) ; y_t(256)] into Hs ----
#pragma unroll
    for (int r = 0; r < 8; r++) {
      const int hv = q + 256 * r;
      const int row = hv >> 6, col = (hv & 63) * 8;
      *(bf16x8*)&Hs[row][col] = *(const bf16x8*)(hglob + row * Hx + col);
    }
#pragma unroll
    for (int r = 0; r < 4; r++) {
      const int vy = q + 256 * r;
      const int row = vy >> 5, col = (vy & 31) * 8;
      const int tok = (t == 0) ? s0tok : texts[row * Tx + t - 1];
      *(bf16x8*)&Hs[row][Hx + col] = *(const bf16x8*)(embb + (size_t)tok * Ex + col);
    }
    __syncthreads();

    // ---- MFMA: wave (mt, kh): A rows mt*16.., B tiles j=0,1, k-half 384 ----
    f32x4 acc0 = {0.f, 0.f, 0.f, 0.f}, acc1 = {0.f, 0.f, 0.f, 0.f};
    const int kb = kh * 384;
#pragma unroll
    for (int ks = 0; ks < 12; ks++) {
      const int ko = kb + ks * 32 + fk;
      bf16x8 a  = *(const bf16x8*)&Hs[mt * 16 + fm][ko];
      bf16x8 b0 = *(const bf16x8*)&Ws[fm][ko];
      bf16x8 b1 = *(const bf16x8*)&Ws[16 + fm][ko];
      acc0 = MFMA16(a, b0, acc0, 0, 0, 0);
      acc1 = MFMA16(a, b1, acc1, 0, 0, 0);
    }
    if (kh == 1) {
      *(f32x4*)&Red[mt][0][lane * 4] = acc0;
      *(f32x4*)&Red[mt][1][lane * 4] = acc1;
    }
    __syncthreads();
    if (kh == 0) {
      const int cr = (lane >> 4) * 4, cc = lane & 15;
#pragma unroll
      for (int r = 0; r < 4; r++) {
        Cs[mt * 16 + cr + r][cc]      = acc0[r] + Red[mt][0][lane * 4 + r];
        Cs[mt * 16 + cr + r][16 + cc] = acc1[r] + Red[mt][1][lane * 4 + r];
      }
    }
    __syncthreads();

    // ---- epilogue: one thread per (b, u_local); c lives in a register ----
    {
      const float pi = Cs[eb][eu * 4 + 0] + cc2[0];
      const float pf = Cs[eb][eu * 4 + 1] + cc2[512];
      const float pg = Cs[eb][eu * 4 + 2] + cc2[1024];
      const float po = Cs[eb][eu * 4 + 3] + cc2[1536];
      const float cn = sigm(pf) * creg + sigm(pi) * tanhf(pg);
      creg = cn;
      Ht[eb][eu] = (__bf16)(sigm(po) * tanhf(cn));
    }
    __syncthreads();
    if (q < 32) {
      bf16x8 v = *(const bf16x8*)&Ht[q][0];
      *(bf16x8*)(hglob + q * Hx + u0) = v;
      *(bf16x8*)(hs2 + ((size_t)q * Tx + t) * Hx + u0) = v;
    }
    __syncthreads();   // drains each wave's stores (vmcnt) before arrival
    if (t < Tx - 1) {
      if (q == 0) {
        __threadfence();
        __hip_atomic_fetch_add(cnt, 1, __ATOMIC_ACQ_REL, __HIP_MEMORY_SCOPE_AGENT);
        const int target = RBLK * (t + 1);
        while (__hip_atomic_load(cnt, __ATOMIC_ACQUIRE, __HIP_MEMORY_SCOPE_AGENT) < target)
          __builtin_amdgcn_s_sleep(2);
        __threadfence();
      }
      __syncthreads();
    }
  }
}

// ---------------------------------------------------------------------------
// K3: logits = hs(bf16) @ Wv(bf16)^T + bias, MFMA 16x16x32.
// Grid: x = m-tile (fast) so the 32 blocks sharing a B n-tile run together;
// A (4 MB) stays L2/L3-hot -> near-minimal HBM fetch.
// ---------------------------------------------------------------------------
#define PM 128
#define PN 128
#define PK 32
#define PKP 40

__global__ __launch_bounds__(256) void k_proj_mfma(
    const __bf16* __restrict__ A,    // [4096][512]
    const __bf16* __restrict__ Bw,   // [10000][512]
    const float* __restrict__ bias, float* __restrict__ C) {
  __shared__ __bf16 As[PM][PKP];
  __shared__ __bf16 Bs[PN][PKP];
  const int m0 = blockIdx.x * PM;
  const int n0 = blockIdx.y * PN;
  const int t = threadIdx.x;
  const int wave = t >> 6, lane = t & 63;
  const int wm = (wave & 1) * 64, wn = (wave >> 1) * 64;
  const int fm = lane & 15, fk = (lane >> 4) * 8;
  const int sr = t >> 2, sk = (t & 3) * 8;

  const int n1 = min(n0 + sr, Vx - 1);
  const int n2 = min(n0 + sr + 64, Vx - 1);

  f32x4 acc[4][4];
#pragma unroll
  for (int i = 0; i < 4; i++)
#pragma unroll
    for (int j = 0; j < 4; j++) acc[i][j] = (f32x4){0.f, 0.f, 0.f, 0.f};

  for (int k0 = 0; k0 < Hx; k0 += PK) {
    __syncthreads();
    *(bf16x8*)&As[sr][sk]      = *(const bf16x8*)&A[(size_t)(m0 + sr) * Hx + k0 + sk];
    *(bf16x8*)&As[sr + 64][sk] = *(const bf16x8*)&A[(size_t)(m0 + sr + 64) * Hx + k0 + sk];
    *(bf16x8*)&Bs[sr][sk]      = *(const bf16x8*)&Bw[(size_t)n1 * Hx + k0 + sk];
    *(bf16x8*)&Bs[sr + 64][sk] = *(const bf16x8*)&Bw[(size_t)n2 * Hx + k0 + sk];
    __syncthreads();
    bf16x8 af[4], bfr[4];
#pragma unroll
    for (int i = 0; i < 4; i++) af[i]  = *(const bf16x8*)&As[wm + i * 16 + fm][fk];
#pragma unroll
    for (int j = 0; j < 4; j++) bfr[j] = *(const bf16x8*)&Bs[wn + j * 16 + fm][fk];
#pragma unroll
    for (int i = 0; i < 4; i++)
#pragma unroll
      for (int j = 0; j < 4; j++)
        acc[i][j] = MFMA16(af[i], bfr[j], acc[i][j], 0, 0, 0);
  }

  const int cr = (lane >> 4) * 4, cc = lane & 15;
#pragma unroll
  for (int i = 0; i < 4; i++) {
#pragma unroll
    for (int r = 0; r < 4; r++) {
      const int m = m0 + wm + i * 16 + cr + r;
      float* crow = C + (size_t)m * Vx;
#pragma unroll
      for (int j = 0; j < 4; j++) {
        const int n = n0 + wn + j * 16 + cc;
        if (n < Vx) crow[n] = acc[i][j][r] + bias[n];
      }
    }
  }
}

// ---------------------------------------------------------------------------
// Inputs (setup_inputs order):
//  0 text_vectors [32,512] f32   1 texts [32,128] i32   2 lengths (unused)
//  3 start_idx i32               4 emb_table [10000,256] f32
//  5 W_ih [2048,1280] 6 b_ih 7 W_hh [2048,512] 8 b_hh
//  9 Wo_w 10 Wo_b 11 Wh_w 12 Wh_b 13 Wc_w 14 Wc_b 15 Wv_w [10000,512] 16 Wv_b
// Output: logits [32,128,10000] f32. Workspace: ~23 MB.
// ---------------------------------------------------------------------------
extern "C" void kernel_launch(void* const* d_in, const int* in_sizes, int n_in,
                              void* d_out, int out_size, void* d_ws, size_t ws_size,
                              hipStream_t stream) {
  const float* tv     = (const float*)d_in[0];
  const int*   texts  = (const int*)d_in[1];
  const int*   sidx   = (const int*)d_in[3];
  const float* emb    = (const float*)d_in[4];
  const float* W_ih   = (const float*)d_in[5];
  const float* b_ih   = (const float*)d_in[6];
  const float* W_hh   = (const float*)d_in[7];
  const float* b_hh   = (const float*)d_in[8];
  const float* Wo_w   = (const float*)d_in[9];
  const float* Wo_b   = (const float*)d_in[10];
  const float* Wh_w   = (const float*)d_in[11];
  const float* Wh_b   = (const float*)d_in[12];
  const float* Wc_w   = (const float*)d_in[13];
  const float* Wc_b   = (const float*)d_in[14];
  const float* Wv_w   = (const float*)d_in[15];
  const float* Wv_b   = (const float*)d_in[16];
  float* out = (float*)d_out;

  float* ws     = (float*)d_ws;
  float* o      = ws;                 // 16384 f
  float* c0     = o + Bx * Hx;        // 16384 f
  float* constC = c0 + Hx * Bx;       // 65536 f
  int*   cnt    = (int*)(constC + (size_t)Bx * G4);   // 512 f reserved
  __bf16* bfb   = (__bf16*)(ws + 98816);              // 16B-aligned
  __bf16* hglob = bfb;                                // 32*512
  __bf16* hs2   = hglob + Bx * Hx;                    // 4096*512
  __bf16* Wvb   = hs2 + (size_t)Bx * Tx * Hx;         // 10000*512
  __bf16* Whb   = Wvb + (size_t)Vx * Hx;              // 2048*512
  __bf16* embb  = Whb + (size_t)G4 * Hx;              // 10000*256
  __bf16* Wihb  = embb + (size_t)Vx * Ex;             // 2048*256

  hipLaunchKernelGGL(k_cvt, dim3((Vx * Hx / 4 + 255) / 256), dim3(256), 0, stream,
                     Wv_w, Wvb, Vx * Hx);
  hipLaunchKernelGGL(k_cvt, dim3((G4 * Hx / 4 + 255) / 256), dim3(256), 0, stream,
                     W_hh, Whb, G4 * Hx);
  hipLaunchKernelGGL(k_cvt, dim3((Vx * Ex / 4 + 255) / 256), dim3(256), 0, stream,
                     emb, embb, Vx * Ex);
  hipLaunchKernelGGL(k_cvt2d, dim3(G4 * Ex / 4 / 256), dim3(256), 0, stream,
                     W_ih, Wihb);
  hipLaunchKernelGGL(k_init, dim3(192), dim3(256), 0, stream,
                     tv, Wo_w, Wo_b, Wh_w, Wh_b, Wc_w, Wc_b, o, hglob, c0);
  hipLaunchKernelGGL(k_const, dim3(256), dim3(256), 0, stream,
                     tv, o, W_ih, b_ih, b_hh, constC, cnt);
  hipLaunchKernelGGL(k_rec, dim3(RBLK), dim3(256), 0, stream,
                     Whb, Wihb, embb, texts, sidx, constC, c0, hglob, hs2, cnt);
  hipLaunchKernelGGL(k_proj_mfma, dim3((Bx * Tx) / PM, (Vx + PN - 1) / PN), dim3(256), 0, stream,
                     hs2, Wvb, Wv_b, out);
}